// Round 1
// baseline (343.426 us; speedup 1.0000x reference)
//
#include <hip/hip_runtime.h>
#include <math.h>

#define N_ROWS 8192
#define D_DIM  512
#define C_CLS  100

// ---------------- ws layout (float offsets) ----------------
// H      : [0,        262144)   512*512
// sums   : [262144,   313344)   100*512
// counts : [313344,   313472)   100 (padded to 128)
// inv    : [313472,   321664)   8192
// wlogit : [321664,   329856)   8192
// cls    : [329856,   338048)   8192 (int)
#define WS_H      0
#define WS_SUMS   262144
#define WS_COUNTS 313344
#define WS_INV    313472
#define WS_W      321664
#define WS_CLS    329856
#define WS_ZERO_FLOATS (262144 + 51200 + 128)

// -------- K1: per-row softmax max + argmax + class counts --------
// one wave (64 lanes) per row of class_logits [8192, 100]
__global__ void k_softmax(const float* __restrict__ logits,
                          float* __restrict__ wv, int* __restrict__ cls,
                          float* __restrict__ counts) {
    int wave = (blockIdx.x * blockDim.x + threadIdx.x) >> 6;
    int lane = threadIdx.x & 63;
    if (wave >= N_ROWS) return;
    const float* row = logits + (size_t)wave * C_CLS;
    float v1 = row[lane];                               // lane < 100 always
    bool has2 = (lane + 64) < C_CLS;
    float v2 = has2 ? row[lane + 64] : -INFINITY;
    float m; int idx;
    if (v2 > v1) { m = v2; idx = lane + 64; } else { m = v1; idx = lane; }
    #pragma unroll
    for (int off = 32; off >= 1; off >>= 1) {
        float om = __shfl_down(m, off);
        int   oi = __shfl_down(idx, off);
        if (om > m || (om == m && oi < idx)) { m = om; idx = oi; }
    }
    m = __shfl(m, 0);
    idx = __shfl(idx, 0);
    float s = expf(v1 - m) + (has2 ? expf(v2 - m) : 0.0f);
    #pragma unroll
    for (int off = 32; off >= 1; off >>= 1) s += __shfl_down(s, off);
    if (lane == 0) {
        wv[wave] = 1.0f / s;          // max of softmax = 1/sum(exp(l-lmax))
        cls[wave] = idx;
        atomicAdd(&counts[idx], 1.0f);
    }
}

// -------- K2: per-row inverse norm of x [8192, 512] --------
__global__ void k_norm(const float* __restrict__ x, float* __restrict__ inv) {
    int wave = (blockIdx.x * blockDim.x + threadIdx.x) >> 6;
    int lane = threadIdx.x & 63;
    if (wave >= N_ROWS) return;
    const float* row = x + (size_t)wave * D_DIM;
    float ss = 0.f;
    #pragma unroll
    for (int j = 0; j < D_DIM; j += 64) {
        float v = row[j + lane];
        ss += v * v;
    }
    #pragma unroll
    for (int off = 32; off >= 1; off >>= 1) ss += __shfl_down(ss, off);
    if (lane == 0) inv[wave] = 1.0f / fmaxf(sqrtf(ss), 1e-8f);
}

// -------- K3: H[i,j] = sum_k inv[k]*x[k,i]*x[k,j]  (512x512, symmetric) --------
// 64x64 tiles, split-K=8, atomicAdd epilogue. 256 threads, 4x4 acc/thread.
#define G1_SPLIT 8
__global__ __launch_bounds__(256) void k_gemm1(const float* __restrict__ x,
                                               const float* __restrict__ inv,
                                               float* __restrict__ H) {
    __shared__ float As[16][64];
    __shared__ float Bs[16][64];
    int tile = blockIdx.x;            // 0..63
    int i0 = (tile & 7) * 64;
    int j0 = (tile >> 3) * 64;
    int kbeg = blockIdx.y * (N_ROWS / G1_SPLIT);
    int kend = kbeg + (N_ROWS / G1_SPLIT);
    int t = threadIdx.x;
    int lr = t >> 6;                  // 0..3
    int lc = t & 63;
    int ti = t & 15, tj = t >> 4;     // 16x16 thread grid
    float acc[4][4] = {};
    for (int k0 = kbeg; k0 < kend; k0 += 16) {
        #pragma unroll
        for (int kk = 0; kk < 4; kk++) {
            int k = lr + kk * 4;
            float iv = inv[k0 + k];
            const float* xr = x + (size_t)(k0 + k) * D_DIM;
            As[k][lc] = xr[i0 + lc] * iv;
            Bs[k][lc] = xr[j0 + lc];
        }
        __syncthreads();
        #pragma unroll
        for (int k = 0; k < 16; k++) {
            float4 a = *(const float4*)&As[k][ti << 2];
            float4 b = *(const float4*)&Bs[k][tj << 2];
            acc[0][0] += a.x * b.x; acc[0][1] += a.x * b.y; acc[0][2] += a.x * b.z; acc[0][3] += a.x * b.w;
            acc[1][0] += a.y * b.x; acc[1][1] += a.y * b.y; acc[1][2] += a.y * b.z; acc[1][3] += a.y * b.w;
            acc[2][0] += a.z * b.x; acc[2][1] += a.z * b.y; acc[2][2] += a.z * b.z; acc[2][3] += a.z * b.w;
            acc[3][0] += a.w * b.x; acc[3][1] += a.w * b.y; acc[3][2] += a.w * b.z; acc[3][3] += a.w * b.w;
        }
        __syncthreads();
    }
    #pragma unroll
    for (int a = 0; a < 4; a++) {
        int i = i0 + (ti << 2) + a;
        #pragma unroll
        for (int b = 0; b < 4; b++) {
            int j = j0 + (tj << 2) + b;
            atomicAdd(&H[(size_t)i * D_DIM + j], acc[a][b]);
        }
    }
}

// -------- K4: T = x@H ; y = inv[m]*T + x ; atomicAdd w[m]*y into sums[cls[m]] --------
// 128x64 output tiles, K=512, 256 threads, 8x4 acc/thread.
__global__ __launch_bounds__(256) void k_gemm2(const float* __restrict__ x,
                                               const float* __restrict__ H,
                                               const float* __restrict__ inv,
                                               const float* __restrict__ wv,
                                               const int* __restrict__ cls,
                                               float* __restrict__ sums) {
    __shared__ float Xs[16][128];
    __shared__ float Hs[16][64];
    int m0 = blockIdx.x * 128;        // 64 blocks in x
    int j0 = blockIdx.y * 64;         // 8 blocks in y
    int t = threadIdx.x;
    int ti = t & 15, tj = t >> 4;
    float acc[8][4] = {};
    for (int k0 = 0; k0 < D_DIM; k0 += 16) {
        #pragma unroll
        for (int h = 0; h < 2; h++) {
            int m = (t >> 2) + h * 64;
            int kq = (t & 3) * 4;
            float4 v = *(const float4*)&x[(size_t)(m0 + m) * D_DIM + k0 + kq];
            Xs[kq + 0][m] = v.x; Xs[kq + 1][m] = v.y;
            Xs[kq + 2][m] = v.z; Xs[kq + 3][m] = v.w;
        }
        {
            int k = t >> 4;
            int j = (t & 15) * 4;
            *(float4*)&Hs[k][j] = *(const float4*)&H[(size_t)(k0 + k) * D_DIM + j0 + j];
        }
        __syncthreads();
        #pragma unroll
        for (int k = 0; k < 16; k++) {
            float4 b  = *(const float4*)&Hs[k][tj << 2];
            float4 a0 = *(const float4*)&Xs[k][ti << 3];
            float4 a1 = *(const float4*)&Xs[k][(ti << 3) + 4];
            acc[0][0] += a0.x * b.x; acc[0][1] += a0.x * b.y; acc[0][2] += a0.x * b.z; acc[0][3] += a0.x * b.w;
            acc[1][0] += a0.y * b.x; acc[1][1] += a0.y * b.y; acc[1][2] += a0.y * b.z; acc[1][3] += a0.y * b.w;
            acc[2][0] += a0.z * b.x; acc[2][1] += a0.z * b.y; acc[2][2] += a0.z * b.z; acc[2][3] += a0.z * b.w;
            acc[3][0] += a0.w * b.x; acc[3][1] += a0.w * b.y; acc[3][2] += a0.w * b.z; acc[3][3] += a0.w * b.w;
            acc[4][0] += a1.x * b.x; acc[4][1] += a1.x * b.y; acc[4][2] += a1.x * b.z; acc[4][3] += a1.x * b.w;
            acc[5][0] += a1.y * b.x; acc[5][1] += a1.y * b.y; acc[5][2] += a1.y * b.z; acc[5][3] += a1.y * b.w;
            acc[6][0] += a1.z * b.x; acc[6][1] += a1.z * b.y; acc[6][2] += a1.z * b.z; acc[6][3] += a1.z * b.w;
            acc[7][0] += a1.w * b.x; acc[7][1] += a1.w * b.y; acc[7][2] += a1.w * b.z; acc[7][3] += a1.w * b.w;
        }
        __syncthreads();
    }
    #pragma unroll
    for (int r = 0; r < 8; r++) {
        int m = m0 + (ti << 3) + r;
        float iv = inv[m];
        float ww = wv[m];
        int c = cls[m];
        const float* xr = x + (size_t)m * D_DIM;
        #pragma unroll
        for (int cc = 0; cc < 4; cc++) {
            int d = j0 + (tj << 2) + cc;
            float y = iv * acc[r][cc] + xr[d];
            atomicAdd(&sums[(size_t)c * D_DIM + d], ww * y);
        }
    }
}

// -------- K5: prototypes = sums / max(counts,1) (0 if empty) -> d_out[0:51200) --------
__global__ void k_proto(const float* __restrict__ sums,
                        const float* __restrict__ counts,
                        float* __restrict__ out) {
    int i = blockIdx.x * blockDim.x + threadIdx.x;
    if (i >= C_CLS * D_DIM) return;
    int c = i >> 9;                   // /512
    float cnt = counts[c];
    out[i] = (cnt > 0.f) ? sums[i] / fmaxf(cnt, 1.f) : 0.f;
}

// -------- K6: inter[i,j,d] = proto[j,d] - proto[i,d] --------
__global__ void k_inter(const float* __restrict__ proto, float* __restrict__ out) {
    int pair = blockIdx.x;            // 0..9999
    int i = pair / C_CLS;
    int j = pair - i * C_CLS;
    int d = threadIdx.x << 2;         // 128 threads * 4
    float4 pj = *(const float4*)&proto[j * D_DIM + d];
    float4 pi = *(const float4*)&proto[i * D_DIM + d];
    float4 r;
    r.x = pj.x - pi.x; r.y = pj.y - pi.y; r.z = pj.z - pi.z; r.w = pj.w - pi.w;
    *(float4*)&out[(size_t)pair * D_DIM + d] = r;
}

extern "C" void kernel_launch(void* const* d_in, const int* in_sizes, int n_in,
                              void* d_out, int out_size, void* d_ws, size_t ws_size,
                              hipStream_t stream) {
    const float* x      = (const float*)d_in[0];   // [8192, 512]
    const float* logits = (const float*)d_in[1];   // [8192, 100]
    float* out = (float*)d_out;                    // 51200 proto + 5120000 inter
    float* ws  = (float*)d_ws;
    float* H      = ws + WS_H;
    float* sums   = ws + WS_SUMS;
    float* counts = ws + WS_COUNTS;
    float* inv    = ws + WS_INV;
    float* wv     = ws + WS_W;
    int*   cls    = (int*)(ws + WS_CLS);

    hipMemsetAsync(d_ws, 0, WS_ZERO_FLOATS * sizeof(float), stream);
    k_softmax<<<N_ROWS / 4, 256, 0, stream>>>(logits, wv, cls, counts);
    k_norm<<<N_ROWS / 4, 256, 0, stream>>>(x, inv);
    k_gemm1<<<dim3(64, G1_SPLIT), 256, 0, stream>>>(x, inv, H);
    k_gemm2<<<dim3(N_ROWS / 128, D_DIM / 64), 256, 0, stream>>>(x, H, inv, wv, cls, sums);
    k_proto<<<(C_CLS * D_DIM + 255) / 256, 256, 0, stream>>>(sums, counts, out);
    k_inter<<<C_CLS * C_CLS, 128, 0, stream>>>(out, out + C_CLS * D_DIM);
}

// Round 2
// 195.573 us; speedup vs baseline: 1.7560x; 1.7560x over previous
//
#include <hip/hip_runtime.h>
#include <math.h>

#define N_ROWS 8192
#define D_DIM  512
#define C_CLS  100

typedef unsigned short u16;
typedef __attribute__((ext_vector_type(8))) short short8;
typedef __attribute__((ext_vector_type(4))) float floatx4;

// ---------------- ws layout (float offsets), ~52.7 MB ----------------
#define WS_G      0          // 512*512 fp32
#define WS_SUMS   262144     // 100*512
#define WS_COUNTS 313344     // 128
#define WS_INV    313472     // 8192
#define WS_WV     321664     // 8192
#define WS_CLS    329856     // 8192 (int)
#define WS_GH     338048     // 512*512 bf16 (131072 floats)
#define WS_GL     469120
#define WS_XH     600192     // 8192*512 bf16 (2097152 floats each)
#define WS_XL     2697344
#define WS_XTH    4794496    // transposed 512*8192 bf16
#define WS_XTL    6891648
#define WS_NTH    8988800
#define WS_NTL    11085952
#define WS_ZERO_FLOATS 313472   // G + sums + counts

// split fp32 -> bf16 hi (chop) + bf16 lo (chop of remainder); rel err ~2^-16
__device__ __forceinline__ void split2(float v, u16& h, u16& l) {
    unsigned u = __float_as_uint(v);
    h = (u16)(u >> 16);
    float r = v - __uint_as_float(u & 0xFFFF0000u);
    l = (u16)(__float_as_uint(r) >> 16);
}

// -------- K1: per-row softmax max + argmax + class counts --------
__global__ void k_softmax(const float* __restrict__ logits,
                          float* __restrict__ wv, int* __restrict__ cls,
                          float* __restrict__ counts) {
    int wave = (blockIdx.x * blockDim.x + threadIdx.x) >> 6;
    int lane = threadIdx.x & 63;
    if (wave >= N_ROWS) return;
    const float* row = logits + (size_t)wave * C_CLS;
    float v1 = row[lane];
    bool has2 = (lane + 64) < C_CLS;
    float v2 = has2 ? row[lane + 64] : -INFINITY;
    float m; int idx;
    if (v2 > v1) { m = v2; idx = lane + 64; } else { m = v1; idx = lane; }
    #pragma unroll
    for (int off = 32; off >= 1; off >>= 1) {
        float om = __shfl_down(m, off);
        int   oi = __shfl_down(idx, off);
        if (om > m || (om == m && oi < idx)) { m = om; idx = oi; }
    }
    m = __shfl(m, 0);
    idx = __shfl(idx, 0);
    float s = expf(v1 - m) + (has2 ? expf(v2 - m) : 0.0f);
    #pragma unroll
    for (int off = 32; off >= 1; off >>= 1) s += __shfl_down(s, off);
    if (lane == 0) {
        wv[wave] = 1.0f / s;
        cls[wave] = idx;
        atomicAdd(&counts[idx], 1.0f);
    }
}

// -------- K2: per-row inverse norm --------
__global__ void k_norm(const float* __restrict__ x, float* __restrict__ inv) {
    int wave = (blockIdx.x * blockDim.x + threadIdx.x) >> 6;
    int lane = threadIdx.x & 63;
    if (wave >= N_ROWS) return;
    const float* row = x + (size_t)wave * D_DIM;
    float ss = 0.f;
    #pragma unroll
    for (int j = 0; j < D_DIM; j += 64) {
        float v = row[j + lane];
        ss += v * v;
    }
    #pragma unroll
    for (int off = 32; off >= 1; off >>= 1) ss += __shfl_down(ss, off);
    if (lane == 0) inv[wave] = 1.0f / fmaxf(sqrtf(ss), 1e-8f);
}

// -------- K3: split x -> bf16 hi/lo (natural) + transposed x, n=inv*x --------
// 64x64 tiles; LDS-packed (hi<<16|lo) transpose.
#define LDT 65
__global__ __launch_bounds__(256) void k_convert(const float* __restrict__ x,
        const float* __restrict__ inv,
        u16* __restrict__ xh, u16* __restrict__ xl,
        u16* __restrict__ xth, u16* __restrict__ xtl,
        u16* __restrict__ nth, u16* __restrict__ ntl) {
    __shared__ unsigned xt_p[64 * LDT];
    __shared__ unsigned nt_p[64 * LDT];
    int r0 = blockIdx.x * 64, c0 = blockIdx.y * 64;
    int t = threadIdx.x;
    int r = t >> 2, cq = t & 3;
    const float* src = x + (size_t)(r0 + r) * D_DIM + c0 + cq * 16;
    float vv[16];
    {
        float4 a = *(const float4*)(src + 0);
        float4 b = *(const float4*)(src + 4);
        float4 c = *(const float4*)(src + 8);
        float4 d = *(const float4*)(src + 12);
        vv[0]=a.x; vv[1]=a.y; vv[2]=a.z; vv[3]=a.w;
        vv[4]=b.x; vv[5]=b.y; vv[6]=b.z; vv[7]=b.w;
        vv[8]=c.x; vv[9]=c.y; vv[10]=c.z; vv[11]=c.w;
        vv[12]=d.x; vv[13]=d.y; vv[14]=d.z; vv[15]=d.w;
    }
    float iv = inv[r0 + r];
    u16 hh[16], ll[16];
    #pragma unroll
    for (int j = 0; j < 16; ++j) {
        split2(vv[j], hh[j], ll[j]);
        u16 nh, nl;
        split2(iv * vv[j], nh, nl);
        int cl = cq * 16 + j;
        xt_p[cl * LDT + r] = ((unsigned)hh[j] << 16) | ll[j];
        nt_p[cl * LDT + r] = ((unsigned)nh   << 16) | nl;
    }
    // natural hi/lo writes
    {
        size_t base = (size_t)(r0 + r) * D_DIM + c0 + cq * 16;
        uint oh[8], ol[8];
        #pragma unroll
        for (int p = 0; p < 8; ++p) {
            oh[p] = (unsigned)hh[2*p] | ((unsigned)hh[2*p+1] << 16);
            ol[p] = (unsigned)ll[2*p] | ((unsigned)ll[2*p+1] << 16);
        }
        *(uint4*)&xh[base]     = make_uint4(oh[0], oh[1], oh[2], oh[3]);
        *(uint4*)&xh[base + 8] = make_uint4(oh[4], oh[5], oh[6], oh[7]);
        *(uint4*)&xl[base]     = make_uint4(ol[0], ol[1], ol[2], ol[3]);
        *(uint4*)&xl[base + 8] = make_uint4(ol[4], ol[5], ol[6], ol[7]);
    }
    __syncthreads();
    // transposed writes: thread t handles out-row c = t>>2, r-chunk (t&3)*16
    int c = t >> 2, rq = (t & 3) * 16;
    size_t tbase = (size_t)(c0 + c) * N_ROWS + r0 + rq;
    {
        uint oh[8], ol[8];
        #pragma unroll
        for (int p = 0; p < 8; ++p) {
            unsigned d0 = xt_p[c * LDT + rq + 2*p];
            unsigned d1 = xt_p[c * LDT + rq + 2*p + 1];
            oh[p] = (d0 >> 16) | (d1 & 0xFFFF0000u);
            ol[p] = (d0 & 0xFFFFu) | (d1 << 16);
        }
        *(uint4*)&xth[tbase]     = make_uint4(oh[0], oh[1], oh[2], oh[3]);
        *(uint4*)&xth[tbase + 8] = make_uint4(oh[4], oh[5], oh[6], oh[7]);
        *(uint4*)&xtl[tbase]     = make_uint4(ol[0], ol[1], ol[2], ol[3]);
        *(uint4*)&xtl[tbase + 8] = make_uint4(ol[4], ol[5], ol[6], ol[7]);
    }
    {
        uint oh[8], ol[8];
        #pragma unroll
        for (int p = 0; p < 8; ++p) {
            unsigned d0 = nt_p[c * LDT + rq + 2*p];
            unsigned d1 = nt_p[c * LDT + rq + 2*p + 1];
            oh[p] = (d0 >> 16) | (d1 & 0xFFFF0000u);
            ol[p] = (d0 & 0xFFFFu) | (d1 << 16);
        }
        *(uint4*)&nth[tbase]     = make_uint4(oh[0], oh[1], oh[2], oh[3]);
        *(uint4*)&nth[tbase + 8] = make_uint4(oh[4], oh[5], oh[6], oh[7]);
        *(uint4*)&ntl[tbase]     = make_uint4(ol[0], ol[1], ol[2], ol[3]);
        *(uint4*)&ntl[tbase + 8] = make_uint4(ol[4], ol[5], ol[6], ol[7]);
    }
}

// -------- K4: G = ntT @ xt  (512x512, K=8192), split-bf16 3-pass MFMA --------
// 64x64 tiles (8x8) x splitK=8 -> 512 blocks; atomicAdd fp32 epilogue.
#define STR 40   // padded LDS row stride in ush (80 B, 16B-aligned)
__global__ __launch_bounds__(256) void k_gemm1(const u16* __restrict__ nth,
        const u16* __restrict__ ntl, const u16* __restrict__ xth,
        const u16* __restrict__ xtl, float* __restrict__ G) {
    __shared__ u16 Ah[64 * STR], Al[64 * STR], Bh[64 * STR], Bl[64 * STR];
    int i0 = (blockIdx.x & 7) * 64, j0 = (blockIdx.x >> 3) * 64;
    int kb = blockIdx.y * (N_ROWS / 8);
    int t = threadIdx.x, w = t >> 6, l = t & 63;
    int sr = t >> 2, sc = (t & 3) * 8;
    floatx4 acc[4];
    floatx4 zero = {0.f, 0.f, 0.f, 0.f};
    #pragma unroll
    for (int nn = 0; nn < 4; ++nn) acc[nn] = zero;
    for (int s = 0; s < 32; ++s) {
        int ks = kb + s * 32 + sc;
        *(uint4*)&Ah[sr * STR + sc] = *(const uint4*)&nth[(size_t)(i0 + sr) * N_ROWS + ks];
        *(uint4*)&Al[sr * STR + sc] = *(const uint4*)&ntl[(size_t)(i0 + sr) * N_ROWS + ks];
        *(uint4*)&Bh[sr * STR + sc] = *(const uint4*)&xth[(size_t)(j0 + sr) * N_ROWS + ks];
        *(uint4*)&Bl[sr * STR + sc] = *(const uint4*)&xtl[(size_t)(j0 + sr) * N_ROWS + ks];
        __syncthreads();
        int ar = (w * 16 + (l & 15)) * STR + (l >> 4) * 8;
        short8 a_h = *(const short8*)&Ah[ar];
        short8 a_l = *(const short8*)&Al[ar];
        #pragma unroll
        for (int nn = 0; nn < 4; ++nn) {
            int br = (nn * 16 + (l & 15)) * STR + (l >> 4) * 8;
            short8 b_h = *(const short8*)&Bh[br];
            short8 b_l = *(const short8*)&Bl[br];
            acc[nn] = __builtin_amdgcn_mfma_f32_16x16x32_bf16(a_h, b_h, acc[nn], 0, 0, 0);
            acc[nn] = __builtin_amdgcn_mfma_f32_16x16x32_bf16(a_h, b_l, acc[nn], 0, 0, 0);
            acc[nn] = __builtin_amdgcn_mfma_f32_16x16x32_bf16(a_l, b_h, acc[nn], 0, 0, 0);
        }
        __syncthreads();
    }
    int row0 = i0 + w * 16 + (l >> 4) * 4;
    int col0 = j0 + (l & 15);
    #pragma unroll
    for (int nn = 0; nn < 4; ++nn)
        #pragma unroll
        for (int r = 0; r < 4; ++r)
            atomicAdd(&G[(size_t)(row0 + r) * D_DIM + col0 + nn * 16], acc[nn][r]);
}

// -------- K5: split G -> Gh, Gl --------
__global__ void k_split(const float* __restrict__ G, u16* __restrict__ Gh,
                        u16* __restrict__ Gl) {
    int i = blockIdx.x * 256 + threadIdx.x;
    u16 h, l;
    split2(G[i], h, l);
    Gh[i] = h; Gl[i] = l;
}

// -------- K6: T = x@G (G symmetric: B rows = G rows); epilogue scatter --------
// 128x64 tiles -> grid (64, 8); 3-pass split MFMA; K=512.
__global__ __launch_bounds__(256) void k_gemm2(const u16* __restrict__ xh,
        const u16* __restrict__ xl, const u16* __restrict__ Gh,
        const u16* __restrict__ Gl, const float* __restrict__ x,
        const float* __restrict__ inv, const float* __restrict__ wv,
        const int* __restrict__ cls, float* __restrict__ sums) {
    __shared__ u16 Xh[128 * STR], Xl[128 * STR], Bh2[64 * STR], Bl2[64 * STR];
    int m0 = blockIdx.x * 128, j0 = blockIdx.y * 64;
    int t = threadIdx.x, w = t >> 6, l = t & 63;
    int sr = t >> 2, sc = (t & 3) * 8;
    floatx4 acc[2][4];
    floatx4 zero = {0.f, 0.f, 0.f, 0.f};
    #pragma unroll
    for (int mi = 0; mi < 2; ++mi)
        #pragma unroll
        for (int nn = 0; nn < 4; ++nn) acc[mi][nn] = zero;
    for (int s = 0; s < 16; ++s) {
        int ks = s * 32 + sc;
        *(uint4*)&Xh[sr * STR + sc]        = *(const uint4*)&xh[(size_t)(m0 + sr) * D_DIM + ks];
        *(uint4*)&Xh[(64 + sr) * STR + sc] = *(const uint4*)&xh[(size_t)(m0 + 64 + sr) * D_DIM + ks];
        *(uint4*)&Xl[sr * STR + sc]        = *(const uint4*)&xl[(size_t)(m0 + sr) * D_DIM + ks];
        *(uint4*)&Xl[(64 + sr) * STR + sc] = *(const uint4*)&xl[(size_t)(m0 + 64 + sr) * D_DIM + ks];
        *(uint4*)&Bh2[sr * STR + sc]       = *(const uint4*)&Gh[(size_t)(j0 + sr) * D_DIM + ks];
        *(uint4*)&Bl2[sr * STR + sc]       = *(const uint4*)&Gl[(size_t)(j0 + sr) * D_DIM + ks];
        __syncthreads();
        int ar0 = (w * 32 + (l & 15)) * STR + (l >> 4) * 8;
        int ar1 = (w * 32 + 16 + (l & 15)) * STR + (l >> 4) * 8;
        short8 ah0 = *(const short8*)&Xh[ar0];
        short8 al0 = *(const short8*)&Xl[ar0];
        short8 ah1 = *(const short8*)&Xh[ar1];
        short8 al1 = *(const short8*)&Xl[ar1];
        #pragma unroll
        for (int nn = 0; nn < 4; ++nn) {
            int br = (nn * 16 + (l & 15)) * STR + (l >> 4) * 8;
            short8 b_h = *(const short8*)&Bh2[br];
            short8 b_l = *(const short8*)&Bl2[br];
            acc[0][nn] = __builtin_amdgcn_mfma_f32_16x16x32_bf16(ah0, b_h, acc[0][nn], 0, 0, 0);
            acc[0][nn] = __builtin_amdgcn_mfma_f32_16x16x32_bf16(ah0, b_l, acc[0][nn], 0, 0, 0);
            acc[0][nn] = __builtin_amdgcn_mfma_f32_16x16x32_bf16(al0, b_h, acc[0][nn], 0, 0, 0);
            acc[1][nn] = __builtin_amdgcn_mfma_f32_16x16x32_bf16(ah1, b_h, acc[1][nn], 0, 0, 0);
            acc[1][nn] = __builtin_amdgcn_mfma_f32_16x16x32_bf16(ah1, b_l, acc[1][nn], 0, 0, 0);
            acc[1][nn] = __builtin_amdgcn_mfma_f32_16x16x32_bf16(al1, b_h, acc[1][nn], 0, 0, 0);
        }
        __syncthreads();
    }
    int col = j0 + (l & 15);
    #pragma unroll
    for (int mi = 0; mi < 2; ++mi) {
        int rb = m0 + w * 32 + mi * 16 + (l >> 4) * 4;
        #pragma unroll
        for (int r = 0; r < 4; ++r) {
            int m = rb + r;
            float ivm = inv[m], wm = wv[m];
            int cm = cls[m];
            #pragma unroll
            for (int nn = 0; nn < 4; ++nn) {
                int d = col + nn * 16;
                float y = ivm * acc[mi][nn][r] + x[(size_t)m * D_DIM + d];
                atomicAdd(&sums[(size_t)cm * D_DIM + d], wm * y);
            }
        }
    }
}

// -------- K7: prototypes --------
__global__ void k_proto(const float* __restrict__ sums,
                        const float* __restrict__ counts,
                        float* __restrict__ out) {
    int i = blockIdx.x * blockDim.x + threadIdx.x;
    if (i >= C_CLS * D_DIM) return;
    int c = i >> 9;
    float cnt = counts[c];
    out[i] = (cnt > 0.f) ? sums[i] / fmaxf(cnt, 1.f) : 0.f;
}

// -------- K8: inter[i,j,d] = proto[j,d] - proto[i,d] --------
__global__ void k_inter(const float* __restrict__ proto, float* __restrict__ out) {
    int pair = blockIdx.x;
    int i = pair / C_CLS;
    int j = pair - i * C_CLS;
    int d = threadIdx.x << 2;
    float4 pj = *(const float4*)&proto[j * D_DIM + d];
    float4 pi = *(const float4*)&proto[i * D_DIM + d];
    float4 r;
    r.x = pj.x - pi.x; r.y = pj.y - pi.y; r.z = pj.z - pi.z; r.w = pj.w - pi.w;
    *(float4*)&out[(size_t)pair * D_DIM + d] = r;
}

extern "C" void kernel_launch(void* const* d_in, const int* in_sizes, int n_in,
                              void* d_out, int out_size, void* d_ws, size_t ws_size,
                              hipStream_t stream) {
    const float* x      = (const float*)d_in[0];   // [8192, 512]
    const float* logits = (const float*)d_in[1];   // [8192, 100]
    float* out = (float*)d_out;
    float* ws  = (float*)d_ws;
    float* G      = ws + WS_G;
    float* sums   = ws + WS_SUMS;
    float* counts = ws + WS_COUNTS;
    float* inv    = ws + WS_INV;
    float* wv     = ws + WS_WV;
    int*   cls    = (int*)(ws + WS_CLS);
    u16* Gh  = (u16*)(ws + WS_GH);
    u16* Gl  = (u16*)(ws + WS_GL);
    u16* xh  = (u16*)(ws + WS_XH);
    u16* xl  = (u16*)(ws + WS_XL);
    u16* xth = (u16*)(ws + WS_XTH);
    u16* xtl = (u16*)(ws + WS_XTL);
    u16* nth = (u16*)(ws + WS_NTH);
    u16* ntl = (u16*)(ws + WS_NTL);

    hipMemsetAsync(d_ws, 0, WS_ZERO_FLOATS * sizeof(float), stream);
    k_softmax<<<N_ROWS / 4, 256, 0, stream>>>(logits, wv, cls, counts);
    k_norm<<<N_ROWS / 4, 256, 0, stream>>>(x, inv);
    k_convert<<<dim3(128, 8), 256, 0, stream>>>(x, inv, xh, xl, xth, xtl, nth, ntl);
    k_gemm1<<<dim3(64, 8), 256, 0, stream>>>(nth, ntl, xth, xtl, G);
    k_split<<<D_DIM * D_DIM / 256, 256, 0, stream>>>(G, Gh, Gl);
    k_gemm2<<<dim3(64, 8), 256, 0, stream>>>(xh, xl, Gh, Gl, x, inv, wv, cls, sums);
    k_proto<<<(C_CLS * D_DIM + 255) / 256, 256, 0, stream>>>(sums, counts, out);
    k_inter<<<C_CLS * C_CLS, 128, 0, stream>>>(out, out + C_CLS * D_DIM);
}